// Round 2
// baseline (34929.401 us; speedup 1.0000x reference)
//
#include <hip/hip_runtime.h>
#include <math.h>

#define FEAT 512
#define NS   4096
#define NQ   8192
#define NC   64
#define G4   2048   // 4*FEAT
#define SLAB 512    // support-slab width for column softmax

__device__ __forceinline__ float sigf(float x) { return 1.0f / (1.0f + expf(-x)); }

// ---------------- small utility kernels ----------------
__global__ void kcopy(float* __restrict__ dst, const float* __restrict__ src, int n) {
    int i = blockIdx.x * blockDim.x + threadIdx.x;
    int st = gridDim.x * blockDim.x;
    for (; i < n; i += st) dst[i] = src[i];
}

__global__ void kzero(float* __restrict__ dst, int n) {
    int i = blockIdx.x * blockDim.x + threadIdx.x;
    int st = gridDim.x * blockDim.x;
    for (; i < n; i += st) dst[i] = 0.0f;
}

__global__ void klog(float* __restrict__ o, int n) {
    int i = blockIdx.x * blockDim.x + threadIdx.x;
    int st = gridDim.x * blockDim.x;
    for (; i < n; i += st) o[i] = logf(o[i]);
}

// pack Wpack[k*4+g][0:1536] = [Wc_ih[g*512+k][0:1024] | Wc_hh[g*512+k][0:512]]
// bpack[k*4+g] = bc[g*512+k]
__global__ void pack_w(float* __restrict__ Wpack, float* __restrict__ bpack,
                       const float* __restrict__ Wc_ih, const float* __restrict__ Wc_hh,
                       const float* __restrict__ bc) {
    int i = blockIdx.x * blockDim.x + threadIdx.x;
    int st = gridDim.x * blockDim.x;
    const int n = G4 * 1536;
    for (; i < n; i += st) {
        int R = i / 1536, j = i - R * 1536;
        int k = R >> 2, g = R & 3;
        int row2 = g * FEAT + k;
        Wpack[i] = (j < 1024) ? Wc_ih[(size_t)row2 * 1024 + j]
                              : Wc_hh[(size_t)row2 * FEAT + (j - 1024)];
        if (j == 0) bpack[R] = bc[row2];
    }
}

// ---------------- GEMM: C = A @ B^T (+bias) ----------------
// A: [M x K] lda, B: [N x K] ldb, C: [M x N] ldc. M,N mult of 128, K of 8.
__global__ __launch_bounds__(256)
void gemm_abt(const float* __restrict__ A, int lda,
              const float* __restrict__ B, int ldb,
              float* __restrict__ C, int ldc,
              const float* __restrict__ bias, int K)
{
    __shared__ float As[8][128];
    __shared__ float Bs[8][128];
    const int row0 = blockIdx.y * 128;
    const int col0 = blockIdx.x * 128;
    const int tid = threadIdx.x;
    const int tr = tid >> 4, tc = tid & 15;
    float acc[8][8];
#pragma unroll
    for (int i = 0; i < 8; ++i)
#pragma unroll
        for (int j = 0; j < 8; ++j) acc[i][j] = 0.0f;

    const int lr = tid >> 1;
    const int lk = (tid & 1) * 4;
    for (int k0 = 0; k0 < K; k0 += 8) {
        float4 av = *(const float4*)(A + (size_t)(row0 + lr) * lda + k0 + lk);
        float4 bv = *(const float4*)(B + (size_t)(col0 + lr) * ldb + k0 + lk);
        As[lk + 0][lr] = av.x; As[lk + 1][lr] = av.y; As[lk + 2][lr] = av.z; As[lk + 3][lr] = av.w;
        Bs[lk + 0][lr] = bv.x; Bs[lk + 1][lr] = bv.y; Bs[lk + 2][lr] = bv.z; Bs[lk + 3][lr] = bv.w;
        __syncthreads();
#pragma unroll
        for (int kk = 0; kk < 8; ++kk) {
            float4 a0 = *(const float4*)&As[kk][tr * 8];
            float4 a1 = *(const float4*)&As[kk][tr * 8 + 4];
            float4 b0 = *(const float4*)&Bs[kk][tc * 8];
            float4 b1 = *(const float4*)&Bs[kk][tc * 8 + 4];
            float a[8] = {a0.x, a0.y, a0.z, a0.w, a1.x, a1.y, a1.z, a1.w};
            float b[8] = {b0.x, b0.y, b0.z, b0.w, b1.x, b1.y, b1.z, b1.w};
#pragma unroll
            for (int i = 0; i < 8; ++i)
#pragma unroll
                for (int j = 0; j < 8; ++j) acc[i][j] += a[i] * b[j];
        }
        __syncthreads();
    }
#pragma unroll
    for (int i = 0; i < 8; ++i) {
        int row = row0 + tr * 8 + i;
#pragma unroll
        for (int j = 0; j < 8; ++j) {
            int col = col0 + tc * 8 + j;
            float v = acc[i][j];
            if (bias) v += bias[col];
            C[(size_t)row * ldc + col] = v;
        }
    }
}

// ---------------- gate GEMM: C = [f|r|h] @ Wslice^T + bias, K = 1536 ----------------
// B = Wpack + slice*512*1536 (N=512 per slice, grid.x=4), C = gslab [NQ x 512]
__global__ __launch_bounds__(256)
void gemm_gates(const float* __restrict__ f, const float* __restrict__ r,
                const float* __restrict__ h,
                const float* __restrict__ B,   // slice base, ldb = 1536
                float* __restrict__ C,         // ldc = 512
                const float* __restrict__ bias) // slice base
{
    __shared__ float As[8][128];
    __shared__ float Bs[8][128];
    const int row0 = blockIdx.y * 128;
    const int col0 = blockIdx.x * 128;
    const int tid = threadIdx.x;
    const int tr = tid >> 4, tc = tid & 15;
    float acc[8][8];
#pragma unroll
    for (int i = 0; i < 8; ++i)
#pragma unroll
        for (int j = 0; j < 8; ++j) acc[i][j] = 0.0f;

    const int lr = tid >> 1;
    const int lk = (tid & 1) * 4;
    for (int k0 = 0; k0 < 1536; k0 += 8) {
        const int kg = k0 + lk;
        const float* src = (kg < 512) ? (f + (size_t)(row0 + lr) * FEAT + kg)
                         : (kg < 1024) ? (r + (size_t)(row0 + lr) * FEAT + (kg - 512))
                                       : (h + (size_t)(row0 + lr) * FEAT + (kg - 1024));
        float4 av = *(const float4*)src;
        float4 bv = *(const float4*)(B + (size_t)(col0 + lr) * 1536 + kg);
        As[lk + 0][lr] = av.x; As[lk + 1][lr] = av.y; As[lk + 2][lr] = av.z; As[lk + 3][lr] = av.w;
        Bs[lk + 0][lr] = bv.x; Bs[lk + 1][lr] = bv.y; Bs[lk + 2][lr] = bv.z; Bs[lk + 3][lr] = bv.w;
        __syncthreads();
#pragma unroll
        for (int kk = 0; kk < 8; ++kk) {
            float4 a0 = *(const float4*)&As[kk][tr * 8];
            float4 a1 = *(const float4*)&As[kk][tr * 8 + 4];
            float4 b0 = *(const float4*)&Bs[kk][tc * 8];
            float4 b1 = *(const float4*)&Bs[kk][tc * 8 + 4];
            float a[8] = {a0.x, a0.y, a0.z, a0.w, a1.x, a1.y, a1.z, a1.w};
            float b[8] = {b0.x, b0.y, b0.z, b0.w, b1.x, b1.y, b1.z, b1.w};
#pragma unroll
            for (int i = 0; i < 8; ++i)
#pragma unroll
                for (int j = 0; j < 8; ++j) acc[i][j] += a[i] * b[j];
        }
        __syncthreads();
    }
#pragma unroll
    for (int i = 0; i < 8; ++i) {
        int row = row0 + tr * 8 + i;
#pragma unroll
        for (int j = 0; j < 8; ++j) {
            int col = col0 + tc * 8 + j;
            C[(size_t)row * 512 + col] = acc[i][j] + bias[col];
        }
    }
}

// ---------------- GEMM: C (+)= A @ B ----------------
// A: [M x K] lda, B: [K x N] ldb, C: [M x N] ldc. M mult 128, N mult 64, K mult 16.
template<int ACC>
__global__ __launch_bounds__(256)
void gemm_ab(const float* __restrict__ A, int lda,
             const float* __restrict__ B, int ldb,
             float* __restrict__ C, int ldc, int K)
{
    __shared__ float As[16][128];
    __shared__ float Bs[16][64];
    const int row0 = blockIdx.y * 128;
    const int col0 = blockIdx.x * 64;
    const int tid = threadIdx.x;
    const int tr = tid >> 4, tc = tid & 15;
    float acc[8][4];
#pragma unroll
    for (int i = 0; i < 8; ++i)
#pragma unroll
        for (int j = 0; j < 4; ++j) acc[i][j] = 0.0f;

    for (int k0 = 0; k0 < K; k0 += 16) {
#pragma unroll
        for (int p = tid; p < 512; p += 256) {
            int r = p >> 2, kq = (p & 3) * 4;
            float4 av = *(const float4*)(A + (size_t)(row0 + r) * lda + k0 + kq);
            As[kq + 0][r] = av.x; As[kq + 1][r] = av.y; As[kq + 2][r] = av.z; As[kq + 3][r] = av.w;
        }
        {
            int kr = tid >> 4, cq = (tid & 15) * 4;
            float4 bv = *(const float4*)(B + (size_t)(k0 + kr) * ldb + col0 + cq);
            *(float4*)&Bs[kr][cq] = bv;
        }
        __syncthreads();
#pragma unroll
        for (int kk = 0; kk < 16; ++kk) {
            float4 a0 = *(const float4*)&As[kk][tr * 8];
            float4 a1 = *(const float4*)&As[kk][tr * 8 + 4];
            float4 b0 = *(const float4*)&Bs[kk][tc * 4];
            float a[8] = {a0.x, a0.y, a0.z, a0.w, a1.x, a1.y, a1.z, a1.w};
            float b[4] = {b0.x, b0.y, b0.z, b0.w};
#pragma unroll
            for (int i = 0; i < 8; ++i)
#pragma unroll
                for (int j = 0; j < 4; ++j) acc[i][j] += a[i] * b[j];
        }
        __syncthreads();
    }
#pragma unroll
    for (int i = 0; i < 8; ++i) {
        size_t idx = (size_t)(row0 + tr * 8 + i) * ldc + col0 + tc * 4;
#pragma unroll
        for (int j = 0; j < 4; ++j) {
            if (ACC) C[idx + j] += acc[i][j];
            else     C[idx + j]  = acc[i][j];
        }
    }
}

// ---------------- sequential LSTM step (fwd + bwd in one launch) ----------------
__global__ __launch_bounds__(256)
void lstm_step(const float* __restrict__ Xf, const float* __restrict__ Xb,
               const float* __restrict__ Wf, const float* __restrict__ Wb,
               float* __restrict__ hbuf, float* __restrict__ cseq,
               float* __restrict__ G, int t)
{
    const int dir = blockIdx.x >> 5;
    const int blk = blockIdx.x & 31;
    const float* W = dir ? Wb : Wf;
    const int pr = t & 1;
    const float* hp = hbuf + (size_t)(pr * 2 + dir) * FEAT;
    float* hn = hbuf + (size_t)((1 - pr) * 2 + dir) * FEAT;
    float* c = cseq + (size_t)dir * FEAT;
    const int trow = dir ? (NS - 1 - t) : t;
    const float* Xrow = (dir ? Xb : Xf) + (size_t)trow * G4;

    __shared__ float hs[FEAT];
    const int tid = threadIdx.x;
    hs[tid] = hp[tid];
    hs[tid + 256] = hp[tid + 256];
    __syncthreads();

    const int e = tid >> 4, l = tid & 15;
    const int hidx = blk * 16 + e;
    float dots[4];
#pragma unroll
    for (int g = 0; g < 4; ++g) {
        const float* w = W + (size_t)(g * FEAT + hidx) * FEAT;
        float s = 0.0f;
#pragma unroll 8
        for (int k = l; k < FEAT; k += 16) s += w[k] * hs[k];
#pragma unroll
        for (int off = 8; off >= 1; off >>= 1) s += __shfl_xor(s, off, 64);
        dots[g] = s;
    }
    if (l == 0) {
        float gi = dots[0] + Xrow[hidx];
        float gf = dots[1] + Xrow[FEAT + hidx];
        float gg = dots[2] + Xrow[2 * FEAT + hidx];
        float go = dots[3] + Xrow[3 * FEAT + hidx];
        float cold = c[hidx];
        float cn = sigf(gf) * cold + sigf(gi) * tanhf(gg);
        float hv = sigf(go) * tanhf(cn);
        c[hidx] = cn;
        hn[hidx] = hv;
        G[(size_t)trow * FEAT + hidx] += hv;
    }
}

// ---------------- G row-normalize ----------------
__global__ __launch_bounds__(256)
void gnorm(const float* __restrict__ G, float* __restrict__ Gn)
{
    const int row = blockIdx.x;
    const float* g = G + (size_t)row * FEAT;
    float s = 0.0f;
    for (int k = threadIdx.x; k < FEAT; k += 256) { float v = g[k]; s += v * v; }
#pragma unroll
    for (int off = 32; off >= 1; off >>= 1) s += __shfl_xor(s, off, 64);
    __shared__ float red[4];
    if ((threadIdx.x & 63) == 0) red[threadIdx.x >> 6] = s;
    __syncthreads();
    float tot = red[0] + red[1] + red[2] + red[3];
    float inv = 1.0f / (sqrtf(tot) + 1e-5f);
    for (int k = threadIdx.x; k < FEAT; k += 256)
        Gn[(size_t)row * FEAT + k] = g[k] * inv;
}

// ---------------- column softmax stats over a [NQ x SLAB] slab ----------------
__global__ __launch_bounds__(256)
void colstats_partial(const float* __restrict__ A, float* __restrict__ pm,
                      float* __restrict__ pz)
{
    const int col = blockIdx.x * 256 + threadIdx.x;      // 0..511
    const int r0 = blockIdx.y * 256;
    float m = -3.0e38f, z = 0.0f;
    for (int r = 0; r < 256; ++r) {
        float v = A[(size_t)(r0 + r) * SLAB + col];
        if (v > m) { z = z * expf(m - v) + 1.0f; m = v; }
        else       { z += expf(v - m); }
    }
    pm[(size_t)blockIdx.y * SLAB + col] = m;
    pz[(size_t)blockIdx.y * SLAB + col] = z;
}

__global__ __launch_bounds__(256)
void colstats_combine(const float* __restrict__ pm, const float* __restrict__ pz,
                      float* __restrict__ cm, float* __restrict__ ciz)
{
    const int col = blockIdx.x * 256 + threadIdx.x;      // 0..511
    float m = -3.0e38f;
    for (int p = 0; p < 32; ++p) m = fmaxf(m, pm[(size_t)p * SLAB + col]);
    float z = 0.0f;
    for (int p = 0; p < 32; ++p) z += pz[(size_t)p * SLAB + col] * expf(pm[(size_t)p * SLAB + col] - m);
    cm[col] = m;
    ciz[col] = 1.0f / z;
}

__global__ void exp_transform(float* __restrict__ A, const float* __restrict__ cm,
                              const float* __restrict__ ciz)
{
    int i = blockIdx.x * blockDim.x + threadIdx.x;
    const int st = gridDim.x * blockDim.x;
    const int n = NQ * SLAB;
    for (; i < n; i += st) {
        int col = i & (SLAB - 1);
        A[i] = expf(A[i] - cm[col]) * ciz[col];
    }
}

// ---------------- FCE cell on one k-slice of 128 ----------------
// gslab layout: [q][kk*4+g], kk in [0,128). Writes h_next[q][k0+kk], cst same.
__global__ void cell_slice(const float* __restrict__ gslab, float* __restrict__ cst,
                           float* __restrict__ hnext, const float* __restrict__ f,
                           int k0)
{
    int i = blockIdx.x * blockDim.x + threadIdx.x;
    const int st = gridDim.x * blockDim.x;
    const int n = NQ * 128;
    for (; i < n; i += st) {
        int q = i >> 7, kk = i & 127;
        float4 g = *(const float4*)(gslab + (size_t)q * 512 + kk * 4);
        int idx = q * FEAT + k0 + kk;
        float cold = cst[idx];
        float cn = sigf(g.y) * cold + sigf(g.x) * tanhf(g.z);
        float hn = sigf(g.w) * tanhf(cn) + f[idx];
        cst[idx] = cn;
        hnext[idx] = hn;
    }
}

// ---------------- launch ----------------
extern "C" void kernel_launch(void* const* d_in, const int* in_sizes, int n_in,
                              void* d_out, int out_size, void* d_ws, size_t ws_size,
                              hipStream_t stream)
{
    (void)in_sizes; (void)n_in; (void)out_size; (void)ws_size;
    const float* S     = (const float*)d_in[0];
    const float* f     = (const float*)d_in[1];
    const float* Y     = (const float*)d_in[2];
    const float* Wf_ih = (const float*)d_in[3];
    const float* Wf_hh = (const float*)d_in[4];
    const float* bf    = (const float*)d_in[5];
    const float* Wb_ih = (const float*)d_in[6];
    const float* Wb_hh = (const float*)d_in[7];
    const float* bb    = (const float*)d_in[8];
    const float* Wc_ih = (const float*)d_in[9];
    const float* Wc_hh = (const float*)d_in[10];
    const float* bc    = (const float*)d_in[11];
    float* out = (float*)d_out;

    float* ws = (float*)d_ws;
    // region 0: 16M floats, phase A/B = Xf|Xb ; phase C = r|h0|h1|cst
    float* Xf   = ws;                       // 8M
    float* Xb   = ws + (size_t)8 * 1024 * 1024;
    float* r    = ws;                       // 4M each
    float* h0   = ws + (size_t)4 * 1024 * 1024;
    float* h1   = ws + (size_t)8 * 1024 * 1024;
    float* cst  = ws + (size_t)12 * 1024 * 1024;
    size_t off  = (size_t)16 * 1024 * 1024;
    auto alloc = [&](size_t n) { float* p = ws + off; off += n; return p; };
    float* Pslab = alloc((size_t)NQ * SLAB);   // 4M (also gslab)
    float* G     = alloc((size_t)NS * FEAT);   // 2M
    float* Gn    = alloc((size_t)NS * FEAT);   // 2M
    float* Wpack = alloc((size_t)G4 * 1536);   // 3M
    float* bpack = alloc(G4);
    float* pm    = alloc((size_t)32 * SLAB);
    float* pz    = alloc((size_t)32 * SLAB);
    float* cm    = alloc(SLAB);
    float* ciz   = alloc(SLAB);
    float* hbuf  = alloc(4 * FEAT);
    float* cseqb = alloc(2 * FEAT);
    // total ~27.2M floats ~= 109 MB

    const dim3 B256(256);

    // ---- Phase A: Xf = S@Wf_ih^T+bf, Xb = S@Wb_ih^T+bb ----
    gemm_abt<<<dim3(16, 32), B256, 0, stream>>>(S, FEAT, Wf_ih, FEAT, Xf, G4, bf, FEAT);
    gemm_abt<<<dim3(16, 32), B256, 0, stream>>>(S, FEAT, Wb_ih, FEAT, Xb, G4, bb, FEAT);

    // ---- Phase B: sequential bidirectional LSTM; G = S + h_fwd + h_bwd ----
    kcopy<<<dim3(1024), B256, 0, stream>>>(G, S, NS * FEAT);
    kzero<<<dim3(8), B256, 0, stream>>>(hbuf, 6 * FEAT);   // hbuf+cseqb contiguous
    for (int t = 0; t < NS; ++t)
        lstm_step<<<dim3(64), B256, 0, stream>>>(Xf, Xb, Wf_hh, Wb_hh, hbuf, cseqb, G, t);
    gnorm<<<dim3(NS), B256, 0, stream>>>(G, Gn);

    // ---- Phase C prep ----
    pack_w<<<dim3(2048), B256, 0, stream>>>(Wpack, bpack, Wc_ih, Wc_hh, bc);
    kcopy<<<dim3(1024), B256, 0, stream>>>(h0, f, NQ * FEAT);   // h = f
    kzero<<<dim3(1024), B256, 0, stream>>>(cst, NQ * FEAT);     // c = 0

    // ---- Phase C: K=3 FCE iterations ----
    for (int it = 0; it < 3; ++it) {
        float* hc = (it & 1) ? h1 : h0;
        float* hx = (it & 1) ? h0 : h1;
        // r = softmax_col(hc @ G^T) @ G, slab by slab
        for (int sb = 0; sb < NS / SLAB; ++sb) {
            const float* Gs = G + (size_t)sb * SLAB * FEAT;
            gemm_abt<<<dim3(4, 64), B256, 0, stream>>>(hc, FEAT, Gs, FEAT, Pslab, SLAB, nullptr, FEAT);
            colstats_partial<<<dim3(2, 32), B256, 0, stream>>>(Pslab, pm, pz);
            colstats_combine<<<dim3(2), B256, 0, stream>>>(pm, pz, cm, ciz);
            exp_transform<<<dim3(1024), B256, 0, stream>>>(Pslab, cm, ciz);
            if (sb == 0) gemm_ab<0><<<dim3(8, 64), B256, 0, stream>>>(Pslab, SLAB, Gs, FEAT, r, FEAT, SLAB);
            else         gemm_ab<1><<<dim3(8, 64), B256, 0, stream>>>(Pslab, SLAB, Gs, FEAT, r, FEAT, SLAB);
        }
        // gates + cell, 4 k-slices of 128 (N=512 each), gslab aliases Pslab
        for (int sl = 0; sl < 4; ++sl) {
            gemm_gates<<<dim3(4, 64), B256, 0, stream>>>(f, r, hc,
                Wpack + (size_t)sl * 512 * 1536, Pslab, bpack + sl * 512);
            cell_slice<<<dim3(1024), B256, 0, stream>>>(Pslab, cst, hx, f, sl * 128);
        }
    }

    // ---- Phase D: out = log(softmax_col(h @ Gn^T) @ Y), slab by slab ----
    for (int sb = 0; sb < NS / SLAB; ++sb) {
        const float* Gs = Gn + (size_t)sb * SLAB * FEAT;
        gemm_abt<<<dim3(4, 64), B256, 0, stream>>>(h1, FEAT, Gs, FEAT, Pslab, SLAB, nullptr, FEAT);
        colstats_partial<<<dim3(2, 32), B256, 0, stream>>>(Pslab, pm, pz);
        colstats_combine<<<dim3(2), B256, 0, stream>>>(pm, pz, cm, ciz);
        exp_transform<<<dim3(1024), B256, 0, stream>>>(Pslab, cm, ciz);
        if (sb == 0) gemm_ab<0><<<dim3(1, 64), B256, 0, stream>>>(Pslab, SLAB, Y + (size_t)sb * SLAB * NC, NC, out, NC, SLAB);
        else         gemm_ab<1><<<dim3(1, 64), B256, 0, stream>>>(Pslab, SLAB, Y + (size_t)sb * SLAB * NC, NC, out, NC, SLAB);
    }
    klog<<<dim3(512), B256, 0, stream>>>(out, NQ * NC);
}

// Round 3
// 31964.392 us; speedup vs baseline: 1.0928x; 1.0928x over previous
//
#include <hip/hip_runtime.h>
#include <math.h>

#define FEAT 512
#define NS   4096
#define NQ   8192
#define NC   64
#define G4   2048   // 4*FEAT
#define SLAB 512    // support-slab width for column softmax

__device__ __forceinline__ float sigf(float x) { return 1.0f / (1.0f + expf(-x)); }

// ---------------- small utility kernels ----------------
__global__ void kcopy(float* __restrict__ dst, const float* __restrict__ src, int n) {
    int i = blockIdx.x * blockDim.x + threadIdx.x;
    int st = gridDim.x * blockDim.x;
    for (; i < n; i += st) dst[i] = src[i];
}

__global__ void kzero(float* __restrict__ dst, int n) {
    int i = blockIdx.x * blockDim.x + threadIdx.x;
    int st = gridDim.x * blockDim.x;
    for (; i < n; i += st) dst[i] = 0.0f;
}

__global__ void klog(float* __restrict__ o, int n) {
    int i = blockIdx.x * blockDim.x + threadIdx.x;
    int st = gridDim.x * blockDim.x;
    for (; i < n; i += st) o[i] = logf(o[i]);
}

// pack Wpack[k*4+g][0:1536] = [Wc_ih[g*512+k][0:1024] | Wc_hh[g*512+k][0:512]]
// bpack[k*4+g] = bc[g*512+k]
__global__ void pack_w(float* __restrict__ Wpack, float* __restrict__ bpack,
                       const float* __restrict__ Wc_ih, const float* __restrict__ Wc_hh,
                       const float* __restrict__ bc) {
    int i = blockIdx.x * blockDim.x + threadIdx.x;
    int st = gridDim.x * blockDim.x;
    const int n = G4 * 1536;
    for (; i < n; i += st) {
        int R = i / 1536, j = i - R * 1536;
        int k = R >> 2, g = R & 3;
        int row2 = g * FEAT + k;
        Wpack[i] = (j < 1024) ? Wc_ih[(size_t)row2 * 1024 + j]
                              : Wc_hh[(size_t)row2 * FEAT + (j - 1024)];
        if (j == 0) bpack[R] = bc[row2];
    }
}

// ---------------- GEMM: C = A @ B^T (+bias) ----------------
__global__ __launch_bounds__(256)
void gemm_abt(const float* __restrict__ A, int lda,
              const float* __restrict__ B, int ldb,
              float* __restrict__ C, int ldc,
              const float* __restrict__ bias, int K)
{
    __shared__ float As[8][128];
    __shared__ float Bs[8][128];
    const int row0 = blockIdx.y * 128;
    const int col0 = blockIdx.x * 128;
    const int tid = threadIdx.x;
    const int tr = tid >> 4, tc = tid & 15;
    float acc[8][8];
#pragma unroll
    for (int i = 0; i < 8; ++i)
#pragma unroll
        for (int j = 0; j < 8; ++j) acc[i][j] = 0.0f;

    const int lr = tid >> 1;
    const int lk = (tid & 1) * 4;
    for (int k0 = 0; k0 < K; k0 += 8) {
        float4 av = *(const float4*)(A + (size_t)(row0 + lr) * lda + k0 + lk);
        float4 bv = *(const float4*)(B + (size_t)(col0 + lr) * ldb + k0 + lk);
        As[lk + 0][lr] = av.x; As[lk + 1][lr] = av.y; As[lk + 2][lr] = av.z; As[lk + 3][lr] = av.w;
        Bs[lk + 0][lr] = bv.x; Bs[lk + 1][lr] = bv.y; Bs[lk + 2][lr] = bv.z; Bs[lk + 3][lr] = bv.w;
        __syncthreads();
#pragma unroll
        for (int kk = 0; kk < 8; ++kk) {
            float4 a0 = *(const float4*)&As[kk][tr * 8];
            float4 a1 = *(const float4*)&As[kk][tr * 8 + 4];
            float4 b0 = *(const float4*)&Bs[kk][tc * 8];
            float4 b1 = *(const float4*)&Bs[kk][tc * 8 + 4];
            float a[8] = {a0.x, a0.y, a0.z, a0.w, a1.x, a1.y, a1.z, a1.w};
            float b[8] = {b0.x, b0.y, b0.z, b0.w, b1.x, b1.y, b1.z, b1.w};
#pragma unroll
            for (int i = 0; i < 8; ++i)
#pragma unroll
                for (int j = 0; j < 8; ++j) acc[i][j] += a[i] * b[j];
        }
        __syncthreads();
    }
#pragma unroll
    for (int i = 0; i < 8; ++i) {
        int row = row0 + tr * 8 + i;
#pragma unroll
        for (int j = 0; j < 8; ++j) {
            int col = col0 + tc * 8 + j;
            float v = acc[i][j];
            if (bias) v += bias[col];
            C[(size_t)row * ldc + col] = v;
        }
    }
}

// ---------------- gate GEMM: C = [f|r|h] @ Wslice^T + bias, K = 1536 ----------------
__global__ __launch_bounds__(256)
void gemm_gates(const float* __restrict__ f, const float* __restrict__ r,
                const float* __restrict__ h,
                const float* __restrict__ B,   // slice base, ldb = 1536
                float* __restrict__ C,         // ldc = 512
                const float* __restrict__ bias) // slice base
{
    __shared__ float As[8][128];
    __shared__ float Bs[8][128];
    const int row0 = blockIdx.y * 128;
    const int col0 = blockIdx.x * 128;
    const int tid = threadIdx.x;
    const int tr = tid >> 4, tc = tid & 15;
    float acc[8][8];
#pragma unroll
    for (int i = 0; i < 8; ++i)
#pragma unroll
        for (int j = 0; j < 8; ++j) acc[i][j] = 0.0f;

    const int lr = tid >> 1;
    const int lk = (tid & 1) * 4;
    for (int k0 = 0; k0 < 1536; k0 += 8) {
        const int kg = k0 + lk;
        const float* src = (kg < 512) ? (f + (size_t)(row0 + lr) * FEAT + kg)
                         : (kg < 1024) ? (r + (size_t)(row0 + lr) * FEAT + (kg - 512))
                                       : (h + (size_t)(row0 + lr) * FEAT + (kg - 1024));
        float4 av = *(const float4*)src;
        float4 bv = *(const float4*)(B + (size_t)(col0 + lr) * 1536 + kg);
        As[lk + 0][lr] = av.x; As[lk + 1][lr] = av.y; As[lk + 2][lr] = av.z; As[lk + 3][lr] = av.w;
        Bs[lk + 0][lr] = bv.x; Bs[lk + 1][lr] = bv.y; Bs[lk + 2][lr] = bv.z; Bs[lk + 3][lr] = bv.w;
        __syncthreads();
#pragma unroll
        for (int kk = 0; kk < 8; ++kk) {
            float4 a0 = *(const float4*)&As[kk][tr * 8];
            float4 a1 = *(const float4*)&As[kk][tr * 8 + 4];
            float4 b0 = *(const float4*)&Bs[kk][tc * 8];
            float4 b1 = *(const float4*)&Bs[kk][tc * 8 + 4];
            float a[8] = {a0.x, a0.y, a0.z, a0.w, a1.x, a1.y, a1.z, a1.w};
            float b[8] = {b0.x, b0.y, b0.z, b0.w, b1.x, b1.y, b1.z, b1.w};
#pragma unroll
            for (int i = 0; i < 8; ++i)
#pragma unroll
                for (int j = 0; j < 8; ++j) acc[i][j] += a[i] * b[j];
        }
        __syncthreads();
    }
#pragma unroll
    for (int i = 0; i < 8; ++i) {
        int row = row0 + tr * 8 + i;
#pragma unroll
        for (int j = 0; j < 8; ++j) {
            int col = col0 + tc * 8 + j;
            C[(size_t)row * 512 + col] = acc[i][j] + bias[col];
        }
    }
}

// ---------------- GEMM: C (+)= A @ B ----------------
template<int ACC>
__global__ __launch_bounds__(256)
void gemm_ab(const float* __restrict__ A, int lda,
             const float* __restrict__ B, int ldb,
             float* __restrict__ C, int ldc, int K)
{
    __shared__ float As[16][128];
    __shared__ float Bs[16][64];
    const int row0 = blockIdx.y * 128;
    const int col0 = blockIdx.x * 64;
    const int tid = threadIdx.x;
    const int tr = tid >> 4, tc = tid & 15;
    float acc[8][4];
#pragma unroll
    for (int i = 0; i < 8; ++i)
#pragma unroll
        for (int j = 0; j < 4; ++j) acc[i][j] = 0.0f;

    for (int k0 = 0; k0 < K; k0 += 16) {
#pragma unroll
        for (int p = tid; p < 512; p += 256) {
            int r = p >> 2, kq = (p & 3) * 4;
            float4 av = *(const float4*)(A + (size_t)(row0 + r) * lda + k0 + kq);
            As[kq + 0][r] = av.x; As[kq + 1][r] = av.y; As[kq + 2][r] = av.z; As[kq + 3][r] = av.w;
        }
        {
            int kr = tid >> 4, cq = (tid & 15) * 4;
            float4 bv = *(const float4*)(B + (size_t)(k0 + kr) * ldb + col0 + cq);
            *(float4*)&Bs[kr][cq] = bv;
        }
        __syncthreads();
#pragma unroll
        for (int kk = 0; kk < 16; ++kk) {
            float4 a0 = *(const float4*)&As[kk][tr * 8];
            float4 a1 = *(const float4*)&As[kk][tr * 8 + 4];
            float4 b0 = *(const float4*)&Bs[kk][tc * 4];
            float a[8] = {a0.x, a0.y, a0.z, a0.w, a1.x, a1.y, a1.z, a1.w};
            float b[4] = {b0.x, b0.y, b0.z, b0.w};
#pragma unroll
            for (int i = 0; i < 8; ++i)
#pragma unroll
                for (int j = 0; j < 4; ++j) acc[i][j] += a[i] * b[j];
        }
        __syncthreads();
    }
#pragma unroll
    for (int i = 0; i < 8; ++i) {
        size_t idx = (size_t)(row0 + tr * 8 + i) * ldc + col0 + tc * 4;
#pragma unroll
        for (int j = 0; j < 4; ++j) {
            if (ACC) C[idx + j] += acc[i][j];
            else     C[idx + j]  = acc[i][j];
        }
    }
}

// ---------------- persistent bidirectional LSTM ----------------
// grid: 64 blocks (dir = bid>>5, blk = bid&31), 256 threads, 1 block/CU.
// Block stages its 64 W_hh rows (128 KB) in LDS, then runs all NS steps with a
// per-direction device-scope spin barrier. h ping-pongs in hbuf[dir][parity][512].
__global__ __launch_bounds__(256, 1)
void lstm_persist(const float* __restrict__ Xf, const float* __restrict__ Xb,
                  const float* __restrict__ Wf, const float* __restrict__ Wb,
                  float* __restrict__ hbuf, unsigned int* __restrict__ ctrs,
                  float* __restrict__ G)
{
    __shared__ float w_lds[64 * FEAT];   // 128 KB: row (e*4+g), col k
    __shared__ float hs[FEAT];

    const int bid = blockIdx.x;
    const int dir = bid >> 5;
    const int blk = bid & 31;
    const int tid = threadIdx.x;
    const float* W = dir ? Wb : Wf;
    const float* X = dir ? Xb : Xf;
    float* hb = hbuf + dir * 2 * FEAT;                 // [parity][512]
    unsigned int* ctr = ctrs + dir * 32;               // separate cachelines

    // stage W rows: global row (g*512 + blk*16 + e) -> lds row (e*4+g)
    for (int idx = tid * 4; idx < 64 * FEAT; idx += 1024) {
        int row_ld = idx >> 9, col = idx & 511;
        int grow = (row_ld & 3) * FEAT + blk * 16 + (row_ld >> 2);
        float4 wv = *(const float4*)(W + (size_t)grow * FEAT + col);
        *(float4*)&w_lds[row_ld * FEAT + col] = wv;
    }
    __syncthreads();

    const int e = tid >> 4, l = tid & 15;
    const int hidx = blk * 16 + e;
    float c_reg = 0.0f;

    for (int t = 0; t < NS; ++t) {
        const int trow = dir ? (NS - 1 - t) : t;
        const float* Xrow = X + (size_t)trow * G4;
        // prefetch gate-bias terms (independent of h)
        float x0 = 0.f, x1 = 0.f, x2 = 0.f, x3 = 0.f;
        if (l == 0) {
            x0 = Xrow[hidx];            x1 = Xrow[FEAT + hidx];
            x2 = Xrow[2 * FEAT + hidx]; x3 = Xrow[3 * FEAT + hidx];
        }
        // wait for h_{t-1}
        if (t > 0) {
            if (tid == 0) {
                while (__hip_atomic_load(ctr, __ATOMIC_ACQUIRE, __HIP_MEMORY_SCOPE_AGENT)
                       < (unsigned)(32 * t))
                    __builtin_amdgcn_s_sleep(1);
            }
            __syncthreads();
        }
        // load h_{t-1} (agent-scope loads: bypass stale caches)
        const float* hp = hb + (t & 1) * FEAT;
        hs[tid]       = __hip_atomic_load(hp + tid,       __ATOMIC_RELAXED, __HIP_MEMORY_SCOPE_AGENT);
        hs[tid + 256] = __hip_atomic_load(hp + tid + 256, __ATOMIC_RELAXED, __HIP_MEMORY_SCOPE_AGENT);
        __syncthreads();

        float dots[4];
#pragma unroll
        for (int g = 0; g < 4; ++g) {
            const float* w = &w_lds[(e * 4 + g) * FEAT];
            float s = 0.0f;
#pragma unroll
            for (int j = 0; j < 8; ++j) {
                int col = l * 4 + j * 64;
                float4 wv = *(const float4*)&w[col];
                float4 hv = *(const float4*)&hs[col];
                s += wv.x * hv.x + wv.y * hv.y + wv.z * hv.z + wv.w * hv.w;
            }
#pragma unroll
            for (int off = 8; off >= 1; off >>= 1) s += __shfl_xor(s, off, 64);
            dots[g] = s;
        }
        if (l == 0) {
            float gi = dots[0] + x0, gf = dots[1] + x1;
            float gg = dots[2] + x2, go = dots[3] + x3;
            float cn = sigf(gf) * c_reg + sigf(gi) * tanhf(gg);
            float hv = sigf(go) * tanhf(cn);
            c_reg = cn;
            __hip_atomic_store(hb + (1 - (t & 1)) * FEAT + hidx, hv,
                               __ATOMIC_RELAXED, __HIP_MEMORY_SCOPE_AGENT);
            G[(size_t)trow * FEAT + hidx] += hv;
        }
        __syncthreads();   // drains vmcnt: h stores complete before the release add
        if (tid == 0)
            __hip_atomic_fetch_add(ctr, 1u, __ATOMIC_RELEASE, __HIP_MEMORY_SCOPE_AGENT);
    }
}

// ---------------- G row-normalize ----------------
__global__ __launch_bounds__(256)
void gnorm(const float* __restrict__ G, float* __restrict__ Gn)
{
    const int row = blockIdx.x;
    const float* g = G + (size_t)row * FEAT;
    float s = 0.0f;
    for (int k = threadIdx.x; k < FEAT; k += 256) { float v = g[k]; s += v * v; }
#pragma unroll
    for (int off = 32; off >= 1; off >>= 1) s += __shfl_xor(s, off, 64);
    __shared__ float red[4];
    if ((threadIdx.x & 63) == 0) red[threadIdx.x >> 6] = s;
    __syncthreads();
    float tot = red[0] + red[1] + red[2] + red[3];
    float inv = 1.0f / (sqrtf(tot) + 1e-5f);
    for (int k = threadIdx.x; k < FEAT; k += 256)
        Gn[(size_t)row * FEAT + k] = g[k] * inv;
}

// ---------------- column softmax stats over a [NQ x SLAB] slab ----------------
__global__ __launch_bounds__(256)
void colstats_partial(const float* __restrict__ A, float* __restrict__ pm,
                      float* __restrict__ pz)
{
    const int col = blockIdx.x * 256 + threadIdx.x;      // 0..511
    const int r0 = blockIdx.y * 256;
    float m = -3.0e38f, z = 0.0f;
    for (int r = 0; r < 256; ++r) {
        float v = A[(size_t)(r0 + r) * SLAB + col];
        if (v > m) { z = z * expf(m - v) + 1.0f; m = v; }
        else       { z += expf(v - m); }
    }
    pm[(size_t)blockIdx.y * SLAB + col] = m;
    pz[(size_t)blockIdx.y * SLAB + col] = z;
}

__global__ __launch_bounds__(256)
void colstats_combine(const float* __restrict__ pm, const float* __restrict__ pz,
                      float* __restrict__ cm, float* __restrict__ ciz)
{
    const int col = blockIdx.x * 256 + threadIdx.x;      // 0..511
    float m = -3.0e38f;
    for (int p = 0; p < 32; ++p) m = fmaxf(m, pm[(size_t)p * SLAB + col]);
    float z = 0.0f;
    for (int p = 0; p < 32; ++p) z += pz[(size_t)p * SLAB + col] * expf(pm[(size_t)p * SLAB + col] - m);
    cm[col] = m;
    ciz[col] = 1.0f / z;
}

__global__ void exp_transform(float* __restrict__ A, const float* __restrict__ cm,
                              const float* __restrict__ ciz)
{
    int i = blockIdx.x * blockDim.x + threadIdx.x;
    const int st = gridDim.x * blockDim.x;
    const int n = NQ * SLAB;
    for (; i < n; i += st) {
        int col = i & (SLAB - 1);
        A[i] = expf(A[i] - cm[col]) * ciz[col];
    }
}

// ---------------- FCE cell on one k-slice of 128 ----------------
__global__ void cell_slice(const float* __restrict__ gslab, float* __restrict__ cst,
                           float* __restrict__ hnext, const float* __restrict__ f,
                           int k0)
{
    int i = blockIdx.x * blockDim.x + threadIdx.x;
    const int st = gridDim.x * blockDim.x;
    const int n = NQ * 128;
    for (; i < n; i += st) {
        int q = i >> 7, kk = i & 127;
        float4 g = *(const float4*)(gslab + (size_t)q * 512 + kk * 4);
        int idx = q * FEAT + k0 + kk;
        float cold = cst[idx];
        float cn = sigf(g.y) * cold + sigf(g.x) * tanhf(g.z);
        float hn = sigf(g.w) * tanhf(cn) + f[idx];
        cst[idx] = cn;
        hnext[idx] = hn;
    }
}

// ---------------- launch ----------------
extern "C" void kernel_launch(void* const* d_in, const int* in_sizes, int n_in,
                              void* d_out, int out_size, void* d_ws, size_t ws_size,
                              hipStream_t stream)
{
    (void)in_sizes; (void)n_in; (void)out_size; (void)ws_size;
    const float* S     = (const float*)d_in[0];
    const float* f     = (const float*)d_in[1];
    const float* Y     = (const float*)d_in[2];
    const float* Wf_ih = (const float*)d_in[3];
    const float* Wf_hh = (const float*)d_in[4];
    const float* bf    = (const float*)d_in[5];
    const float* Wb_ih = (const float*)d_in[6];
    const float* Wb_hh = (const float*)d_in[7];
    const float* bb    = (const float*)d_in[8];
    const float* Wc_ih = (const float*)d_in[9];
    const float* Wc_hh = (const float*)d_in[10];
    const float* bc    = (const float*)d_in[11];
    float* out = (float*)d_out;

    float* ws = (float*)d_ws;
    // region 0: 16M floats, phase A/B = Xf|Xb ; phase C = r|h0|h1|cst
    float* Xf   = ws;                       // 8M
    float* Xb   = ws + (size_t)8 * 1024 * 1024;
    float* r    = ws;                       // 4M each
    float* h0   = ws + (size_t)4 * 1024 * 1024;
    float* h1   = ws + (size_t)8 * 1024 * 1024;
    float* cst  = ws + (size_t)12 * 1024 * 1024;
    size_t off  = (size_t)16 * 1024 * 1024;
    auto alloc = [&](size_t n) { float* p = ws + off; off += n; return p; };
    float* Pslab = alloc((size_t)NQ * SLAB);   // 4M (also gslab)
    float* G     = alloc((size_t)NS * FEAT);   // 2M
    float* Gn    = alloc((size_t)NS * FEAT);   // 2M
    float* Wpack = alloc((size_t)G4 * 1536);   // 3M
    float* bpack = alloc(G4);
    float* pm    = alloc((size_t)32 * SLAB);
    float* pz    = alloc((size_t)32 * SLAB);
    float* cm    = alloc(SLAB);
    float* ciz   = alloc(SLAB);
    float* hbuf  = alloc(4 * FEAT);            // [dir][parity][512]
    float* ctrs  = alloc(64);                  // 2 counters, cacheline-separated

    const dim3 B256(256);

    // ---- Phase A: Xf = S@Wf_ih^T+bf, Xb = S@Wb_ih^T+bb ----
    gemm_abt<<<dim3(16, 32), B256, 0, stream>>>(S, FEAT, Wf_ih, FEAT, Xf, G4, bf, FEAT);
    gemm_abt<<<dim3(16, 32), B256, 0, stream>>>(S, FEAT, Wb_ih, FEAT, Xb, G4, bb, FEAT);

    // ---- Phase B: persistent bidirectional LSTM; G = S + h_fwd + h_bwd ----
    kcopy<<<dim3(1024), B256, 0, stream>>>(G, S, NS * FEAT);
    kzero<<<dim3(8), B256, 0, stream>>>(hbuf, 4 * FEAT + 64);  // hbuf + ctrs contiguous
    lstm_persist<<<dim3(64), B256, 0, stream>>>(Xf, Xb, Wf_hh, Wb_hh, hbuf,
                                                (unsigned int*)ctrs, G);
    gnorm<<<dim3(NS), B256, 0, stream>>>(G, Gn);

    // ---- Phase C prep ----
    pack_w<<<dim3(2048), B256, 0, stream>>>(Wpack, bpack, Wc_ih, Wc_hh, bc);
    kcopy<<<dim3(1024), B256, 0, stream>>>(h0, f, NQ * FEAT);   // h = f
    kzero<<<dim3(1024), B256, 0, stream>>>(cst, NQ * FEAT);     // c = 0

    // ---- Phase C: K=3 FCE iterations ----
    for (int it = 0; it < 3; ++it) {
        float* hc = (it & 1) ? h1 : h0;
        float* hx = (it & 1) ? h0 : h1;
        // r = softmax_col(hc @ G^T) @ G, slab by slab
        for (int sb = 0; sb < NS / SLAB; ++sb) {
            const float* Gs = G + (size_t)sb * SLAB * FEAT;
            gemm_abt<<<dim3(4, 64), B256, 0, stream>>>(hc, FEAT, Gs, FEAT, Pslab, SLAB, nullptr, FEAT);
            colstats_partial<<<dim3(2, 32), B256, 0, stream>>>(Pslab, pm, pz);
            colstats_combine<<<dim3(2), B256, 0, stream>>>(pm, pz, cm, ciz);
            exp_transform<<<dim3(1024), B256, 0, stream>>>(Pslab, cm, ciz);
            if (sb == 0) gemm_ab<0><<<dim3(8, 64), B256, 0, stream>>>(Pslab, SLAB, Gs, FEAT, r, FEAT, SLAB);
            else         gemm_ab<1><<<dim3(8, 64), B256, 0, stream>>>(Pslab, SLAB, Gs, FEAT, r, FEAT, SLAB);
        }
        // gates + cell, 4 k-slices of 128 (N=512 each), gslab aliases Pslab
        for (int sl = 0; sl < 4; ++sl) {
            gemm_gates<<<dim3(4, 64), B256, 0, stream>>>(f, r, hc,
                Wpack + (size_t)sl * 512 * 1536, Pslab, bpack + sl * 512);
            cell_slice<<<dim3(1024), B256, 0, stream>>>(Pslab, cst, hx, f, sl * 128);
        }
    }

    // ---- Phase D: out = log(softmax_col(h @ Gn^T) @ Y), slab by slab ----
    for (int sb = 0; sb < NS / SLAB; ++sb) {
        const float* Gs = Gn + (size_t)sb * SLAB * FEAT;
        gemm_abt<<<dim3(4, 64), B256, 0, stream>>>(h1, FEAT, Gs, FEAT, Pslab, SLAB, nullptr, FEAT);
        colstats_partial<<<dim3(2, 32), B256, 0, stream>>>(Pslab, pm, pz);
        colstats_combine<<<dim3(2), B256, 0, stream>>>(pm, pz, cm, ciz);
        exp_transform<<<dim3(1024), B256, 0, stream>>>(Pslab, cm, ciz);
        if (sb == 0) gemm_ab<0><<<dim3(1, 64), B256, 0, stream>>>(Pslab, SLAB, Y + (size_t)sb * SLAB * NC, NC, out, NC, SLAB);
        else         gemm_ab<1><<<dim3(1, 64), B256, 0, stream>>>(Pslab, SLAB, Y + (size_t)sb * SLAB * NC, NC, out, NC, SLAB);
    }
    klog<<<dim3(512), B256, 0, stream>>>(out, NQ * NC);
}